// Round 1
// baseline (563.107 us; speedup 1.0000x reference)
//
#include <hip/hip_runtime.h>
#include <hip/hip_bf16.h>
#include <math.h>

typedef __bf16 bf16;
typedef __bf16 bf16x8 __attribute__((ext_vector_type(8)));
typedef float f32x4 __attribute__((ext_vector_type(4)));

#define NB 2
#define LSEQ 2048
#define NH 32
#define NKVH 8
#define HD 64
#define DMODEL 2048
#define CONVD 3072
#define NPROJ 5152
#define NPADN 5248
#define NCHUNK 16
#define CHUNK 128
#define ROWS 4096
#define EPSF 1e-5f

__device__ __forceinline__ float fsilu(float x) { return x / (1.0f + __expf(-x)); }

__device__ __forceinline__ void gld_lds16(void* g, void* l) {
  __builtin_amdgcn_global_load_lds(
      (__attribute__((address_space(1))) void*)g,
      (__attribute__((address_space(3))) void*)l, 16, 0, 0);
}

// ---------------- casts ----------------
__global__ void cast_bf16_kernel(const float* __restrict__ src, bf16* __restrict__ dst, int n) {
  int stride = gridDim.x * blockDim.x;
  for (int i = blockIdx.x * blockDim.x + threadIdx.x; i < n; i += stride)
    dst[i] = (bf16)src[i];
}

__global__ void cast_w1_kernel(const float* __restrict__ src, bf16* __restrict__ dst) {
  long total = (long)NPADN * DMODEL;
  long stride = (long)gridDim.x * blockDim.x;
  for (long i = blockIdx.x * (long)blockDim.x + threadIdx.x; i < total; i += stride) {
    int n = (int)(i >> 11);  // /2048
    if (n < NPROJ) dst[i] = (bf16)src[i];
    else dst[i] = (bf16)0.0f;
  }
}

// ---------------- GEMM: C[M,N] = A[M,K] * B[N,K]^T (bf16 in, fp32 out) ----------------
// m97-style: 128x128 tile, BK=64, 4 waves (2x2), 16x16x32 bf16 MFMA, global_load_lds w=16.
__global__ __launch_bounds__(256) void gemm_bt_kernel(
    const bf16* __restrict__ A, const bf16* __restrict__ B, float* __restrict__ C,
    int M, int N, int K) {
  __shared__ __align__(16) bf16 As[128 * 64];
  __shared__ __align__(16) bf16 Bs[128 * 64];
  const int tid = threadIdx.x;
  const int lane = tid & 63;
  const int wave = tid >> 6;
  const int wm = wave >> 1, wn = wave & 1;
  const int bm = blockIdx.y, bn = blockIdx.x;

  f32x4 acc[4][4] = {};

  const bf16* Ab = A + (long)bm * 128 * K;
  const bf16* Bb = B + (long)bn * 128 * K;

  for (int k0 = 0; k0 < K; k0 += 64) {
#pragma unroll
    for (int j = 0; j < 4; ++j) {
      int q = wave * 4 + j;
      int e = q * 512 + lane * 8;   // element index in 128x64 tile image
      int row = e >> 6;
      int col = e & 63;
      gld_lds16((void*)(Ab + (long)row * K + k0 + col), (void*)(As + e));
      gld_lds16((void*)(Bb + (long)row * K + k0 + col), (void*)(Bs + e));
    }
    __syncthreads();
#pragma unroll
    for (int ks = 0; ks < 64; ks += 32) {
      bf16x8 af[4], bfb[4];
#pragma unroll
      for (int mi = 0; mi < 4; ++mi)
        af[mi] = *(const bf16x8*)(As + (wm * 64 + mi * 16 + (lane & 15)) * 64 + ks + (lane >> 4) * 8);
#pragma unroll
      for (int ni = 0; ni < 4; ++ni)
        bfb[ni] = *(const bf16x8*)(Bs + (wn * 64 + ni * 16 + (lane & 15)) * 64 + ks + (lane >> 4) * 8);
#pragma unroll
      for (int mi = 0; mi < 4; ++mi)
#pragma unroll
        for (int ni = 0; ni < 4; ++ni)
          acc[mi][ni] = __builtin_amdgcn_mfma_f32_16x16x32_bf16(af[mi], bfb[ni], acc[mi][ni], 0, 0, 0);
    }
    __syncthreads();
  }

#pragma unroll
  for (int mi = 0; mi < 4; ++mi) {
    int rbase = bm * 128 + wm * 64 + mi * 16 + (lane >> 4) * 4;
#pragma unroll
    for (int ni = 0; ni < 4; ++ni) {
      int col = bn * 128 + wn * 64 + ni * 16 + (lane & 15);
#pragma unroll
      for (int r = 0; r < 4; ++r)
        C[(long)(rbase + r) * N + col] = acc[mi][ni][r];
    }
  }
}

// ---------------- conv (k=2, causal) + SiLU + softplus(dt) ----------------
__global__ __launch_bounds__(256) void conv_kernel(
    const float* __restrict__ proj, const float* __restrict__ conv_w,
    const float* __restrict__ conv_b, const float* __restrict__ dt_bias,
    const float* __restrict__ A_log, float* __restrict__ vkq,
    float* __restrict__ dtb, float* __restrict__ adtb) {
  int row = blockIdx.x;            // b*LSEQ + l
  int l = row & (LSEQ - 1);
  const float* cur = proj + (long)row * NPADN;
  const float* prev = cur - NPADN;
  for (int c = threadIdx.x; c < CONVD; c += 256) {
    float pv = (l > 0) ? prev[c] : 0.0f;
    float x = pv * conv_w[c * 2 + 0] + cur[c] * conv_w[c * 2 + 1] + conv_b[c];
    vkq[(long)row * CONVD + c] = fsilu(x);
  }
  if (threadIdx.x < NH) {
    int h = threadIdx.x;
    float raw = cur[CONVD + DMODEL + h] + dt_bias[h];
    float dtv = (raw > 20.0f) ? raw : log1pf(__expf(raw));
    dtb[row * NH + h] = dtv;
    adtb[row * NH + h] = -__expf(A_log[h]) * dtv;
  }
}

// inclusive scan of 128 values in LDS (all 256 threads must call: uniform barriers)
__device__ __forceinline__ void scan128(float* a, int tid) {
#pragma unroll
  for (int off = 1; off < CHUNK; off <<= 1) {
    float add = 0.f;
    if (tid >= off && tid < CHUNK) add = a[tid - off];
    __syncthreads();
    if (tid >= off && tid < CHUNK) a[tid] += add;
    __syncthreads();
  }
}

// ---------------- SSD phase A: per-chunk states [p,n] ----------------
__global__ __launch_bounds__(256) void ssd_states_kernel(
    const float* __restrict__ vkq, const float* __restrict__ dtb,
    const float* __restrict__ adtb, float* __restrict__ states, float* __restrict__ asum) {
  __shared__ float kw[CHUNK][HD];
  __shared__ float xv[CHUNK][HD];
  __shared__ float acs[CHUNK];
  __shared__ float dts[CHUNK];
  int bid = blockIdx.x;                       // ((b*16 + c)*32 + h)
  int h = bid & 31, c = (bid >> 5) & 15, b = bid >> 9;
  int kvh = h >> 2;
  int tid = threadIdx.x;
  long rowbase = (long)b * LSEQ + c * CHUNK;
  if (tid < CHUNK) {
    acs[tid] = adtb[(rowbase + tid) * NH + h];
    dts[tid] = dtb[(rowbase + tid) * NH + h];
  }
  __syncthreads();
  scan128(acs, tid);
  float atot = acs[CHUNK - 1];
  for (int e = tid; e < CHUNK * HD; e += 256) {
    int j = e >> 6, p = e & 63;
    long roff = (rowbase + j) * (long)CONVD;
    kw[j][p] = vkq[roff + 512 + kvh * HD + p] * __expf(atot - acs[j]);
    xv[j][p] = vkq[roff + kvh * HD + p] * dts[j];
  }
  __syncthreads();
  int p0 = (tid >> 4) * 4, n0 = (tid & 15) * 4;
  float acc[4][4] = {{0.f}};
  for (int j = 0; j < CHUNK; ++j) {
    float xr[4], kr[4];
#pragma unroll
    for (int u = 0; u < 4; ++u) { xr[u] = xv[j][p0 + u]; kr[u] = kw[j][n0 + u]; }
#pragma unroll
    for (int u = 0; u < 4; ++u)
#pragma unroll
      for (int v = 0; v < 4; ++v) acc[u][v] += xr[u] * kr[v];
  }
  float* sout = states + (long)bid * (HD * HD);
#pragma unroll
  for (int u = 0; u < 4; ++u)
#pragma unroll
    for (int v = 0; v < 4; ++v)
      sout[(p0 + u) * HD + n0 + v] = acc[u][v];
  if (tid == 0) asum[(b * NH + h) * NCHUNK + c] = atot;
}

// ---------------- SSD phase B: inter-chunk state scan ----------------
__global__ __launch_bounds__(256) void ssd_scan_kernel(
    const float* __restrict__ states, const float* __restrict__ asum,
    float* __restrict__ sprev) {
  int bid = blockIdx.x;                       // b*256 + h*8 + s
  int s = bid & 7, h = (bid >> 3) & 31, b = bid >> 8;
  int e0 = s * 512 + threadIdx.x;
  int e1 = e0 + 256;
  float S0 = 0.f, S1 = 0.f;
  const float* as = asum + (b * NH + h) * NCHUNK;
  for (int c = 0; c < NCHUNK; ++c) {
    long off = ((long)((b * NCHUNK + c) * NH + h)) * (HD * HD);
    float g = __expf(as[c]);
    sprev[off + e0] = S0;
    sprev[off + e1] = S1;
    S0 = S0 * g + states[off + e0];
    S1 = S1 * g + states[off + e1];
  }
}

// ---------------- SSD phase C: Yd + Yo + RMSNorm + gate -> bf16 ----------------
__global__ __launch_bounds__(256) void ssd_out_kernel(
    const float* __restrict__ vkq, const float* __restrict__ proj,
    const float* __restrict__ dtb, const float* __restrict__ adtb,
    const float* __restrict__ sprev, const float* __restrict__ gnw,
    bf16* __restrict__ yg) {
  __shared__ float Cq[CHUNK][65];
  __shared__ float BX[CHUNK][65];     // B (k), later reused as X (v*dt)
  __shared__ float G[CHUNK][129];
  __shared__ float Sp[HD][65];
  __shared__ float acs[CHUNK];
  __shared__ float dts[CHUNK];
  __shared__ float part[CHUNK][8];

  int bid = blockIdx.x;                       // ((b*16 + c)*32 + h)
  int h = bid & 31, c = (bid >> 5) & 15, b = bid >> 9;
  int kvh = h >> 2;
  int tid = threadIdx.x;
  long rowbase = (long)b * LSEQ + c * CHUNK;

  if (tid < CHUNK) {
    acs[tid] = adtb[(rowbase + tid) * NH + h];
    dts[tid] = dtb[(rowbase + tid) * NH + h];
  }
  for (int e = tid; e < CHUNK * HD; e += 256) {
    int j = e >> 6, p = e & 63;
    long roff = (rowbase + j) * (long)CONVD;
    Cq[j][p] = vkq[roff + 1024 + h * HD + p];
    BX[j][p] = vkq[roff + 512 + kvh * HD + p];
  }
  {
    long soff = ((long)((b * NCHUNK + c) * NH + h)) * (HD * HD);
    for (int e = tid; e < HD * HD; e += 256) Sp[e >> 6][e & 63] = sprev[soff + e];
  }
  __syncthreads();
  scan128(acs, tid);

  // G[i][j] = (j<=i) ? (Cq_i . B_j) * exp(acs_i - acs_j) : 0
  {
    int ti = (tid & 15) * 8, tj = (tid >> 4) * 8;
    float a2[8][8] = {{0.f}};
    for (int n = 0; n < HD; ++n) {
      float cu[8], bv[8];
#pragma unroll
      for (int u = 0; u < 8; ++u) { cu[u] = Cq[ti + u][n]; bv[u] = BX[tj + u][n]; }
#pragma unroll
      for (int u = 0; u < 8; ++u)
#pragma unroll
        for (int v = 0; v < 8; ++v) a2[u][v] += cu[u] * bv[v];
    }
#pragma unroll
    for (int u = 0; u < 8; ++u)
#pragma unroll
      for (int v = 0; v < 8; ++v) {
        int i = ti + u, j = tj + v;
        G[i][j] = (j <= i) ? a2[u][v] * __expf(acs[i] - acs[j]) : 0.f;
      }
  }
  __syncthreads();
  // overwrite BX with X = v * dt
  for (int e = tid; e < CHUNK * HD; e += 256) {
    int j = e >> 6, p = e & 63;
    BX[j][p] = vkq[(rowbase + j) * (long)CONVD + kvh * HD + p] * dts[j];
  }
  __syncthreads();

  int i0 = (tid >> 3) * 4, p0 = (tid & 7) * 8;
  float accD[4][8] = {{0.f}};
  float accO[4][8] = {{0.f}};
  for (int j = 0; j < CHUNK; ++j) {
    float g4[4], x8[8];
#pragma unroll
    for (int u = 0; u < 4; ++u) g4[u] = G[i0 + u][j];
#pragma unroll
    for (int v = 0; v < 8; ++v) x8[v] = BX[j][p0 + v];
#pragma unroll
    for (int u = 0; u < 4; ++u)
#pragma unroll
      for (int v = 0; v < 8; ++v) accD[u][v] += g4[u] * x8[v];
  }
  for (int n = 0; n < HD; ++n) {
    float c4[4], s8[8];
#pragma unroll
    for (int u = 0; u < 4; ++u) c4[u] = Cq[i0 + u][n];
#pragma unroll
    for (int v = 0; v < 8; ++v) s8[v] = Sp[p0 + v][n];
#pragma unroll
    for (int u = 0; u < 4; ++u)
#pragma unroll
      for (int v = 0; v < 8; ++v) accO[u][v] += c4[u] * s8[v];
  }
  float y[4][8];
#pragma unroll
  for (int u = 0; u < 4; ++u) {
    float ei = __expf(acs[i0 + u]);
    float ss = 0.f;
#pragma unroll
    for (int v = 0; v < 8; ++v) {
      y[u][v] = accD[u][v] + ei * accO[u][v];
      ss += y[u][v] * y[u][v];
    }
    part[i0 + u][tid & 7] = ss;
  }
  __syncthreads();
#pragma unroll
  for (int u = 0; u < 4; ++u) {
    float s = 0.f;
#pragma unroll
    for (int t2 = 0; t2 < 8; ++t2) s += part[i0 + u][t2];
    float rs = rsqrtf(s * (1.0f / HD) + EPSF);
    long row = rowbase + i0 + u;
#pragma unroll
    for (int v = 0; v < 8; ++v) {
      int p = p0 + v;
      float gval = proj[row * (long)NPADN + CONVD + h * HD + p];
      float val = y[u][v] * rs * gnw[p] * fsilu(gval);
      yg[row * (long)DMODEL + h * HD + p] = (bf16)val;
    }
  }
}

// ---------------- launch ----------------
extern "C" void kernel_launch(void* const* d_in, const int* in_sizes, int n_in,
                              void* d_out, int out_size, void* d_ws, size_t ws_size,
                              hipStream_t stream) {
  const float* hs      = (const float*)d_in[0];
  const float* W1      = (const float*)d_in[1];
  const float* conv_w  = (const float*)d_in[2];
  const float* conv_b  = (const float*)d_in[3];
  const float* dt_bias = (const float*)d_in[4];
  const float* A_log   = (const float*)d_in[5];
  const float* gnw     = (const float*)d_in[6];
  const float* Wo      = (const float*)d_in[7];

  char* p = (char*)d_ws;
  bf16* hs_b   = (bf16*)p;  p += (long)ROWS * DMODEL * 2;
  bf16* w1_b   = (bf16*)p;  p += (long)NPADN * DMODEL * 2;
  bf16* wo_b   = (bf16*)p;  p += (long)DMODEL * DMODEL * 2;
  float* proj  = (float*)p; p += (long)ROWS * NPADN * 4;
  float* vkq   = (float*)p; p += (long)ROWS * CONVD * 4;
  float* dtb   = (float*)p; p += (long)ROWS * NH * 4;
  float* adtb  = (float*)p; p += (long)ROWS * NH * 4;
  float* st    = (float*)p; p += (long)NB * NCHUNK * NH * HD * HD * 4;
  float* sprev = (float*)p; p += (long)NB * NCHUNK * NH * HD * HD * 4;
  float* asum  = (float*)p; p += (long)NB * NH * NCHUNK * 4;
  bf16* yg     = (bf16*)p;  p += (long)ROWS * DMODEL * 2;

  cast_bf16_kernel<<<2048, 256, 0, stream>>>(hs, hs_b, ROWS * DMODEL);
  cast_w1_kernel<<<2048, 256, 0, stream>>>(W1, w1_b);
  cast_bf16_kernel<<<1024, 256, 0, stream>>>(Wo, wo_b, DMODEL * DMODEL);

  gemm_bt_kernel<<<dim3(NPADN / 128, ROWS / 128), 256, 0, stream>>>(
      hs_b, w1_b, proj, ROWS, NPADN, DMODEL);

  conv_kernel<<<ROWS, 256, 0, stream>>>(proj, conv_w, conv_b, dt_bias, A_log, vkq, dtb, adtb);

  ssd_states_kernel<<<NB * NCHUNK * NH, 256, 0, stream>>>(vkq, dtb, adtb, st, asum);
  ssd_scan_kernel<<<NB * NH * 8, 256, 0, stream>>>(st, asum, sprev);
  ssd_out_kernel<<<NB * NCHUNK * NH, 256, 0, stream>>>(vkq, proj, dtb, adtb, sprev, gnw, yg);

  gemm_bt_kernel<<<dim3(DMODEL / 128, ROWS / 128), 256, 0, stream>>>(
      yg, wo_b, (float*)d_out, ROWS, DMODEL, DMODEL);
}

// Round 2
// 480.885 us; speedup vs baseline: 1.1710x; 1.1710x over previous
//
#include <hip/hip_runtime.h>
#include <hip/hip_bf16.h>
#include <math.h>

typedef __bf16 bf16;
typedef __bf16 bf16x8 __attribute__((ext_vector_type(8)));
typedef float f32x4 __attribute__((ext_vector_type(4)));

#define NB 2
#define LSEQ 2048
#define NH 32
#define NKVH 8
#define HD 64
#define DMODEL 2048
#define CONVD 3072
#define NPROJ 5152
#define NPADN 5248
#define NCHUNK 16
#define CHUNK 128
#define ROWS 4096
#define EPSF 1e-5f

__device__ __forceinline__ float fsilu(float x) { return x / (1.0f + __expf(-x)); }

__device__ __forceinline__ void gld_lds16(void* g, void* l) {
  __builtin_amdgcn_global_load_lds(
      (__attribute__((address_space(1))) void*)g,
      (__attribute__((address_space(3))) void*)l, 16, 0, 0);
}

// ---------------- casts ----------------
__global__ void cast_bf16_kernel(const float* __restrict__ src, bf16* __restrict__ dst, int n) {
  int stride = gridDim.x * blockDim.x;
  for (int i = blockIdx.x * blockDim.x + threadIdx.x; i < n; i += stride)
    dst[i] = (bf16)src[i];
}

__global__ void cast_w1_kernel(const float* __restrict__ src, bf16* __restrict__ dst) {
  long total = (long)NPADN * DMODEL;
  long stride = (long)gridDim.x * blockDim.x;
  for (long i = blockIdx.x * (long)blockDim.x + threadIdx.x; i < total; i += stride) {
    int n = (int)(i >> 11);  // /2048
    if (n < NPROJ) dst[i] = (bf16)src[i];
    else dst[i] = (bf16)0.0f;
  }
}

// ---------------- GEMM: C[M,N] = A[M,K] * B[N,K]^T (bf16 in, fp32 out) ----------------
__global__ __launch_bounds__(256) void gemm_bt_kernel(
    const bf16* __restrict__ A, const bf16* __restrict__ B, float* __restrict__ C,
    int M, int N, int K) {
  __shared__ __align__(16) bf16 As[128 * 64];
  __shared__ __align__(16) bf16 Bs[128 * 64];
  const int tid = threadIdx.x;
  const int lane = tid & 63;
  const int wave = tid >> 6;
  const int wm = wave >> 1, wn = wave & 1;
  const int bm = blockIdx.y, bn = blockIdx.x;

  f32x4 acc[4][4] = {};

  const bf16* Ab = A + (long)bm * 128 * K;
  const bf16* Bb = B + (long)bn * 128 * K;

  for (int k0 = 0; k0 < K; k0 += 64) {
#pragma unroll
    for (int j = 0; j < 4; ++j) {
      int q = wave * 4 + j;
      int e = q * 512 + lane * 8;
      int row = e >> 6;
      int col = e & 63;
      gld_lds16((void*)(Ab + (long)row * K + k0 + col), (void*)(As + e));
      gld_lds16((void*)(Bb + (long)row * K + k0 + col), (void*)(Bs + e));
    }
    __syncthreads();
#pragma unroll
    for (int ks = 0; ks < 64; ks += 32) {
      bf16x8 af[4], bfb[4];
#pragma unroll
      for (int mi = 0; mi < 4; ++mi)
        af[mi] = *(const bf16x8*)(As + (wm * 64 + mi * 16 + (lane & 15)) * 64 + ks + (lane >> 4) * 8);
#pragma unroll
      for (int ni = 0; ni < 4; ++ni)
        bfb[ni] = *(const bf16x8*)(Bs + (wn * 64 + ni * 16 + (lane & 15)) * 64 + ks + (lane >> 4) * 8);
#pragma unroll
      for (int mi = 0; mi < 4; ++mi)
#pragma unroll
        for (int ni = 0; ni < 4; ++ni)
          acc[mi][ni] = __builtin_amdgcn_mfma_f32_16x16x32_bf16(af[mi], bfb[ni], acc[mi][ni], 0, 0, 0);
    }
    __syncthreads();
  }

#pragma unroll
  for (int mi = 0; mi < 4; ++mi) {
    int rbase = bm * 128 + wm * 64 + mi * 16 + (lane >> 4) * 4;
#pragma unroll
    for (int ni = 0; ni < 4; ++ni) {
      int col = bn * 128 + wn * 64 + ni * 16 + (lane & 15);
#pragma unroll
      for (int r = 0; r < 4; ++r)
        C[(long)(rbase + r) * N + col] = acc[mi][ni][r];
    }
  }
}

// ---------------- conv (k=2, causal) + SiLU + softplus(dt) ----------------
__global__ __launch_bounds__(256) void conv_kernel(
    const float* __restrict__ proj, const float* __restrict__ conv_w,
    const float* __restrict__ conv_b, const float* __restrict__ dt_bias,
    const float* __restrict__ A_log, float* __restrict__ vkq,
    float* __restrict__ dtb, float* __restrict__ adtb) {
  int row = blockIdx.x;
  int l = row & (LSEQ - 1);
  const float* cur = proj + (long)row * NPADN;
  const float* prev = cur - NPADN;
  for (int c = threadIdx.x; c < CONVD; c += 256) {
    float pv = (l > 0) ? prev[c] : 0.0f;
    float x = pv * conv_w[c * 2 + 0] + cur[c] * conv_w[c * 2 + 1] + conv_b[c];
    vkq[(long)row * CONVD + c] = fsilu(x);
  }
  if (threadIdx.x < NH) {
    int h = threadIdx.x;
    float raw = cur[CONVD + DMODEL + h] + dt_bias[h];
    float dtv = (raw > 20.0f) ? raw : log1pf(__expf(raw));
    dtb[row * NH + h] = dtv;
    adtb[row * NH + h] = -__expf(A_log[h]) * dtv;
  }
}

// inclusive scan of 128 values in LDS (all 256 threads must call)
__device__ __forceinline__ void scan128(float* a, int tid) {
#pragma unroll
  for (int off = 1; off < CHUNK; off <<= 1) {
    float add = 0.f;
    if (tid >= off && tid < CHUNK) add = a[tid - off];
    __syncthreads();
    if (tid >= off && tid < CHUNK) a[tid] += add;
    __syncthreads();
  }
}

// ---------------- SSD phase A (MFMA): per-chunk states S[p][n] ----------------
// S[p][n] = sum_j X[j][p] * Kw[j][n];  A-op = Xt[p][j], B-op = Kwt[n][j], K=128
__global__ __launch_bounds__(256) void ssd_states_kernel(
    const float* __restrict__ vkq, const float* __restrict__ dtb,
    const float* __restrict__ adtb, float* __restrict__ states, float* __restrict__ asum) {
  __shared__ __align__(16) bf16 Xt[64 * 136];
  __shared__ __align__(16) bf16 Kwt[64 * 136];
  __shared__ float acs[CHUNK];
  __shared__ float dts[CHUNK];
  int bid = blockIdx.x;                       // ((b*16 + c)*32 + h)
  int h = bid & 31, c = (bid >> 5) & 15, b = bid >> 9;
  int kvh = h >> 2;
  int tid = threadIdx.x;
  int lane = tid & 63, wave = tid >> 6;
  long rowbase = (long)b * LSEQ + c * CHUNK;
  if (tid < CHUNK) {
    acs[tid] = adtb[(rowbase + tid) * NH + h];
    dts[tid] = dtb[(rowbase + tid) * NH + h];
  }
  __syncthreads();
  scan128(acs, tid);
  float atot = acs[CHUNK - 1];
  for (int e = tid; e < CHUNK * HD; e += 256) {
    int j = e >> 6, p = e & 63;
    long roff = (rowbase + j) * (long)CONVD;
    float kv = vkq[roff + 512 + kvh * HD + p] * __expf(atot - acs[j]);
    float xv = vkq[roff + kvh * HD + p] * dts[j];
    Kwt[p * 136 + j] = (bf16)kv;   // p plays the n role
    Xt[p * 136 + j] = (bf16)xv;
  }
  __syncthreads();

  // wave w: p-rows [w*16, w*16+16), n full 64
  f32x4 sacc[4] = {};
#pragma unroll
  for (int ks = 0; ks < CHUNK; ks += 32) {
    bf16x8 af = *(const bf16x8*)(Xt + (wave * 16 + (lane & 15)) * 136 + ks + (lane >> 4) * 8);
    bf16x8 bf_[4];
#pragma unroll
    for (int ni = 0; ni < 4; ++ni)
      bf_[ni] = *(const bf16x8*)(Kwt + (ni * 16 + (lane & 15)) * 136 + ks + (lane >> 4) * 8);
#pragma unroll
    for (int ni = 0; ni < 4; ++ni)
      sacc[ni] = __builtin_amdgcn_mfma_f32_16x16x32_bf16(af, bf_[ni], sacc[ni], 0, 0, 0);
  }
  float* sout = states + (long)bid * (HD * HD);
#pragma unroll
  for (int ni = 0; ni < 4; ++ni) {
    int n = ni * 16 + (lane & 15);
#pragma unroll
    for (int r = 0; r < 4; ++r) {
      int p = wave * 16 + (lane >> 4) * 4 + r;
      sout[p * HD + n] = sacc[ni][r];
    }
  }
  if (tid == 0) asum[(b * NH + h) * NCHUNK + c] = atot;
}

// ---------------- SSD phase B: inter-chunk state scan ----------------
__global__ __launch_bounds__(256) void ssd_scan_kernel(
    const float* __restrict__ states, const float* __restrict__ asum,
    float* __restrict__ sprev) {
  int bid = blockIdx.x;                       // b*256 + h*8 + s
  int s = bid & 7, h = (bid >> 3) & 31, b = bid >> 8;
  int e0 = s * 512 + threadIdx.x;
  int e1 = e0 + 256;
  float S0 = 0.f, S1 = 0.f;
  const float* as = asum + (b * NH + h) * NCHUNK;
  for (int c = 0; c < NCHUNK; ++c) {
    long off = ((long)((b * NCHUNK + c) * NH + h)) * (HD * HD);
    float g = __expf(as[c]);
    sprev[off + e0] = S0;
    sprev[off + e1] = S1;
    S0 = S0 * g + states[off + e0];
    S1 = S1 * g + states[off + e1];
  }
}

// ---------------- SSD phase C (MFMA): Yd + Yo + RMSNorm + gate -> bf16 ----------------
__global__ __launch_bounds__(256) void ssd_out_kernel(
    const float* __restrict__ vkq, const float* __restrict__ proj,
    const float* __restrict__ dtb, const float* __restrict__ adtb,
    const float* __restrict__ sprev, const float* __restrict__ gnw,
    bf16* __restrict__ yg) {
  __shared__ __align__(16) bf16 Cq[128 * 72];    // [i][n] stride 72 — A-op for G and Yo
  __shared__ __align__(16) bf16 BmXt[128 * 72];  // Bm: [j][n] stride 72; later Xt: [p][j] stride 136 (64 rows)
  __shared__ __align__(16) bf16 G[128 * 136];    // [i][j] stride 136 — A-op for Yd
  __shared__ __align__(16) bf16 Sp[64 * 72];     // [p][n] stride 72 — B-op for Yo
  __shared__ float acs[CHUNK];
  __shared__ float dts[CHUNK];
  __shared__ float part[CHUNK][2];
  __shared__ float rs_l[CHUNK];

  int bid = blockIdx.x;                       // ((b*16 + c)*32 + h)
  int h = bid & 31, c = (bid >> 5) & 15, b = bid >> 9;
  int kvh = h >> 2;
  int tid = threadIdx.x;
  int lane = tid & 63, wave = tid >> 6;
  int wm = wave >> 1, wn = wave & 1;
  long rowbase = (long)b * LSEQ + c * CHUNK;

  if (tid < CHUNK) {
    acs[tid] = adtb[(rowbase + tid) * NH + h];
    dts[tid] = dtb[(rowbase + tid) * NH + h];
  }
  for (int e = tid; e < CHUNK * HD; e += 256) {
    int j = e >> 6, p = e & 63;
    long roff = (rowbase + j) * (long)CONVD;
    Cq[j * 72 + p] = (bf16)vkq[roff + 1024 + h * HD + p];
    BmXt[j * 72 + p] = (bf16)vkq[roff + 512 + kvh * HD + p];
  }
  {
    long soff = ((long)((b * NCHUNK + c) * NH + h)) * (HD * HD);
    for (int e = tid; e < HD * HD; e += 256) Sp[(e >> 6) * 72 + (e & 63)] = (bf16)sprev[soff + e];
  }
  __syncthreads();
  scan128(acs, tid);

  // --- G = Cq . Bm^T  (128x128, K=64), each wave 4x4 tiles ---
  {
    f32x4 gacc[4][4] = {};
#pragma unroll
    for (int ks = 0; ks < HD; ks += 32) {
      bf16x8 af[4], bf_[4];
#pragma unroll
      for (int mi = 0; mi < 4; ++mi)
        af[mi] = *(const bf16x8*)(Cq + (wm * 64 + mi * 16 + (lane & 15)) * 72 + ks + (lane >> 4) * 8);
#pragma unroll
      for (int ni = 0; ni < 4; ++ni)
        bf_[ni] = *(const bf16x8*)(BmXt + (wn * 64 + ni * 16 + (lane & 15)) * 72 + ks + (lane >> 4) * 8);
#pragma unroll
      for (int mi = 0; mi < 4; ++mi)
#pragma unroll
        for (int ni = 0; ni < 4; ++ni)
          gacc[mi][ni] = __builtin_amdgcn_mfma_f32_16x16x32_bf16(af[mi], bf_[ni], gacc[mi][ni], 0, 0, 0);
    }
    // mask + decay, write to G (bf16)
#pragma unroll
    for (int mi = 0; mi < 4; ++mi) {
#pragma unroll
      for (int r = 0; r < 4; ++r) {
        int i = wm * 64 + mi * 16 + (lane >> 4) * 4 + r;
        float ai = acs[i];
#pragma unroll
        for (int ni = 0; ni < 4; ++ni) {
          int j = wn * 64 + ni * 16 + (lane & 15);
          float gv = (j <= i) ? gacc[mi][ni][r] * __expf(ai - acs[j]) : 0.f;
          G[i * 136 + j] = (bf16)gv;
        }
      }
    }
  }
  __syncthreads();   // all waves done with Bm; G fully written

  // --- overwrite BmXt with Xt[p][j] = v[j][p] * dt[j], stride 136 ---
  for (int e = tid; e < CHUNK * HD; e += 256) {
    int j = e >> 6, p = e & 63;
    BmXt[p * 136 + j] = (bf16)(vkq[(rowbase + j) * (long)CONVD + kvh * HD + p] * dts[j]);
  }
  __syncthreads();

  // --- Yd = G . Xt^T (128x64, K=128); Yo = Cq . Sp^T (128x64, K=64) ---
  // wave tiling: wm over i (64 rows), wn over p (32 cols); mi in [0,4), ni in [0,2)
  f32x4 yacc[4][2] = {};
  f32x4 oacc[4][2] = {};
#pragma unroll
  for (int ks = 0; ks < CHUNK; ks += 32) {
    bf16x8 af[4], bf_[2];
#pragma unroll
    for (int mi = 0; mi < 4; ++mi)
      af[mi] = *(const bf16x8*)(G + (wm * 64 + mi * 16 + (lane & 15)) * 136 + ks + (lane >> 4) * 8);
#pragma unroll
    for (int ni = 0; ni < 2; ++ni)
      bf_[ni] = *(const bf16x8*)(BmXt + (wn * 32 + ni * 16 + (lane & 15)) * 136 + ks + (lane >> 4) * 8);
#pragma unroll
    for (int mi = 0; mi < 4; ++mi)
#pragma unroll
      for (int ni = 0; ni < 2; ++ni)
        yacc[mi][ni] = __builtin_amdgcn_mfma_f32_16x16x32_bf16(af[mi], bf_[ni], yacc[mi][ni], 0, 0, 0);
  }
#pragma unroll
  for (int ks = 0; ks < HD; ks += 32) {
    bf16x8 af[4], bf_[2];
#pragma unroll
    for (int mi = 0; mi < 4; ++mi)
      af[mi] = *(const bf16x8*)(Cq + (wm * 64 + mi * 16 + (lane & 15)) * 72 + ks + (lane >> 4) * 8);
#pragma unroll
    for (int ni = 0; ni < 2; ++ni)
      bf_[ni] = *(const bf16x8*)(Sp + (wn * 32 + ni * 16 + (lane & 15)) * 72 + ks + (lane >> 4) * 8);
#pragma unroll
    for (int mi = 0; mi < 4; ++mi)
#pragma unroll
      for (int ni = 0; ni < 2; ++ni)
        oacc[mi][ni] = __builtin_amdgcn_mfma_f32_16x16x32_bf16(af[mi], bf_[ni], oacc[mi][ni], 0, 0, 0);
  }

  // --- combine, RMSNorm partials ---
  float yv[4][2][4];
#pragma unroll
  for (int mi = 0; mi < 4; ++mi) {
#pragma unroll
    for (int r = 0; r < 4; ++r) {
      int i = wm * 64 + mi * 16 + (lane >> 4) * 4 + r;
      float ei = __expf(acs[i]);
      float s = 0.f;
#pragma unroll
      for (int ni = 0; ni < 2; ++ni) {
        float v = yacc[mi][ni][r] + ei * oacc[mi][ni][r];
        yv[mi][ni][r] = v;
        s += v * v;
      }
      // reduce over the 16 lanes of this quad-group (masks 1,2,4,8 stay in-group)
      s += __shfl_xor(s, 1, 64);
      s += __shfl_xor(s, 2, 64);
      s += __shfl_xor(s, 4, 64);
      s += __shfl_xor(s, 8, 64);
      if ((lane & 15) == 0) part[i][wn] = s;
    }
  }
  __syncthreads();
  if (tid < CHUNK) rs_l[tid] = rsqrtf((part[tid][0] + part[tid][1]) * (1.0f / HD) + EPSF);
  __syncthreads();

  // --- gate + store ---
#pragma unroll
  for (int mi = 0; mi < 4; ++mi) {
#pragma unroll
    for (int r = 0; r < 4; ++r) {
      int i = wm * 64 + mi * 16 + (lane >> 4) * 4 + r;
      long row = rowbase + i;
      float rs = rs_l[i];
#pragma unroll
      for (int ni = 0; ni < 2; ++ni) {
        int p = wn * 32 + ni * 16 + (lane & 15);
        float gval = proj[row * (long)NPADN + CONVD + h * HD + p];
        float val = yv[mi][ni][r] * rs * gnw[p] * fsilu(gval);
        yg[row * (long)DMODEL + h * HD + p] = (bf16)val;
      }
    }
  }
}

// ---------------- launch ----------------
extern "C" void kernel_launch(void* const* d_in, const int* in_sizes, int n_in,
                              void* d_out, int out_size, void* d_ws, size_t ws_size,
                              hipStream_t stream) {
  const float* hs      = (const float*)d_in[0];
  const float* W1      = (const float*)d_in[1];
  const float* conv_w  = (const float*)d_in[2];
  const float* conv_b  = (const float*)d_in[3];
  const float* dt_bias = (const float*)d_in[4];
  const float* A_log   = (const float*)d_in[5];
  const float* gnw     = (const float*)d_in[6];
  const float* Wo      = (const float*)d_in[7];

  char* p = (char*)d_ws;
  bf16* hs_b   = (bf16*)p;  p += (long)ROWS * DMODEL * 2;
  bf16* w1_b   = (bf16*)p;  p += (long)NPADN * DMODEL * 2;
  bf16* wo_b   = (bf16*)p;  p += (long)DMODEL * DMODEL * 2;
  float* proj  = (float*)p; p += (long)ROWS * NPADN * 4;
  float* vkq   = (float*)p; p += (long)ROWS * CONVD * 4;
  float* dtb   = (float*)p; p += (long)ROWS * NH * 4;
  float* adtb  = (float*)p; p += (long)ROWS * NH * 4;
  float* st    = (float*)p; p += (long)NB * NCHUNK * NH * HD * HD * 4;
  float* sprev = (float*)p; p += (long)NB * NCHUNK * NH * HD * HD * 4;
  float* asum  = (float*)p; p += (long)NB * NH * NCHUNK * 4;
  bf16* yg     = (bf16*)p;  p += (long)ROWS * DMODEL * 2;

  cast_bf16_kernel<<<2048, 256, 0, stream>>>(hs, hs_b, ROWS * DMODEL);
  cast_w1_kernel<<<2048, 256, 0, stream>>>(W1, w1_b);
  cast_bf16_kernel<<<1024, 256, 0, stream>>>(Wo, wo_b, DMODEL * DMODEL);

  gemm_bt_kernel<<<dim3(NPADN / 128, ROWS / 128), 256, 0, stream>>>(
      hs_b, w1_b, proj, ROWS, NPADN, DMODEL);

  conv_kernel<<<ROWS, 256, 0, stream>>>(proj, conv_w, conv_b, dt_bias, A_log, vkq, dtb, adtb);

  ssd_states_kernel<<<NB * NCHUNK * NH, 256, 0, stream>>>(vkq, dtb, adtb, st, asum);
  ssd_scan_kernel<<<NB * NH * 8, 256, 0, stream>>>(st, asum, sprev);
  ssd_out_kernel<<<NB * NCHUNK * NH, 256, 0, stream>>>(vkq, proj, dtb, adtb, sprev, gnw, yg);

  gemm_bt_kernel<<<dim3(DMODEL / 128, ROWS / 128), 256, 0, stream>>>(
      yg, wo_b, (float*)d_out, ROWS, DMODEL, DMODEL);
}

// Round 3
// 454.776 us; speedup vs baseline: 1.2382x; 1.0574x over previous
//
#include <hip/hip_runtime.h>
#include <hip/hip_bf16.h>
#include <math.h>

typedef __bf16 bf16;
typedef __bf16 bf16x4 __attribute__((ext_vector_type(4)));
typedef __bf16 bf16x8 __attribute__((ext_vector_type(8)));
typedef float f32x4 __attribute__((ext_vector_type(4)));

#define NB 2
#define LSEQ 2048
#define NH 32
#define NKVH 8
#define HD 64
#define DMODEL 2048
#define CONVD 3072
#define NPROJ 5152
#define NPADN 5248
#define NCHUNK 16
#define CHUNK 128
#define ROWS 4096
#define EPSF 1e-5f

__device__ __forceinline__ float fsilu(float x) { return x / (1.0f + __expf(-x)); }

__device__ __forceinline__ void gld_lds16(const void* g, void* l) {
  __builtin_amdgcn_global_load_lds(
      (const __attribute__((address_space(1))) void*)g,
      (__attribute__((address_space(3))) void*)l, 16, 0, 0);
}

// ---------------- casts ----------------
__global__ void cast_bf16_kernel(const float* __restrict__ src, bf16* __restrict__ dst, int n) {
  int stride = gridDim.x * blockDim.x;
  for (int i = blockIdx.x * blockDim.x + threadIdx.x; i < n; i += stride)
    dst[i] = (bf16)src[i];
}

__global__ void cast_w1_kernel(const float* __restrict__ src, bf16* __restrict__ dst) {
  long total = (long)NPADN * DMODEL;
  long stride = (long)gridDim.x * blockDim.x;
  for (long i = blockIdx.x * (long)blockDim.x + threadIdx.x; i < total; i += stride) {
    int n = (int)(i >> 11);  // /2048
    if (n < NPROJ) dst[i] = (bf16)src[i];
    else dst[i] = (bf16)0.0f;
  }
}

// ---------------- GEMM: C[M,N] = A[M,K] * B[N,K]^T (bf16 in, OutT out) ----------------
// 128x128 tile, BK=64, 4 waves, 16x16x32 MFMA.
// XOR bank swizzle: global chunk cg of row r stored at LDS chunk cg^(r&7).
// 1D grid with supertile swizzle (GM=8 m-tiles per group) for L2 reuse.
template <typename OutT>
__global__ __launch_bounds__(256) void gemm_bt_kernel(
    const bf16* __restrict__ A, const bf16* __restrict__ B, OutT* __restrict__ C,
    int M, int N, int K, int ntx) {
  __shared__ __align__(16) bf16 As[128 * 64];
  __shared__ __align__(16) bf16 Bs[128 * 64];
  const int tid = threadIdx.x;
  const int lane = tid & 63;
  const int wave = tid >> 6;
  const int wm = wave >> 1, wn = wave & 1;

  // supertile swizzle
  const int GM = 8;
  int lid = blockIdx.x;
  int group = GM * ntx;
  int gid = lid / group;
  int rem = lid - gid * group;
  int bm = gid * GM + (rem % GM);
  int bn = rem / GM;

  f32x4 acc[4][4] = {};

  const bf16* Ab = A + (long)bm * 128 * K;
  const bf16* Bb = B + (long)bn * 128 * K;

  // staging: lane loads global chunk colsw of its row (xor swizzle)
  const int colsw = (((lane & 7) ^ ((lane >> 3) & 7)) << 3);
  // fragment base offsets (elements); ks2 flips bit 5, mi adds 1024
  const int fbA = (wm * 64 + (lane & 15)) * 64 + ((((lane >> 4) ^ (lane & 7))) << 3);
  const int fbB = (wn * 64 + (lane & 15)) * 64 + ((((lane >> 4) ^ (lane & 7))) << 3);

  for (int k0 = 0; k0 < K; k0 += 64) {
#pragma unroll
    for (int j = 0; j < 4; ++j) {
      int q = wave * 4 + j;
      int e = q * 512 + lane * 8;        // LDS element offset
      int row = q * 8 + (lane >> 3);     // tile row
      gld_lds16((const void*)(Ab + (long)row * K + k0 + colsw), (void*)(As + e));
      gld_lds16((const void*)(Bb + (long)row * K + k0 + colsw), (void*)(Bs + e));
    }
    __syncthreads();
#pragma unroll
    for (int ks2 = 0; ks2 < 2; ++ks2) {
      bf16x8 af[4], bfb[4];
#pragma unroll
      for (int mi = 0; mi < 4; ++mi)
        af[mi] = *(const bf16x8*)(As + ((fbA + mi * 1024) ^ (ks2 << 5)));
#pragma unroll
      for (int ni = 0; ni < 4; ++ni)
        bfb[ni] = *(const bf16x8*)(Bs + ((fbB + ni * 1024) ^ (ks2 << 5)));
#pragma unroll
      for (int mi = 0; mi < 4; ++mi)
#pragma unroll
        for (int ni = 0; ni < 4; ++ni)
          acc[mi][ni] = __builtin_amdgcn_mfma_f32_16x16x32_bf16(af[mi], bfb[ni], acc[mi][ni], 0, 0, 0);
    }
    __syncthreads();
  }

#pragma unroll
  for (int mi = 0; mi < 4; ++mi) {
    int rbase = bm * 128 + wm * 64 + mi * 16 + (lane >> 4) * 4;
#pragma unroll
    for (int ni = 0; ni < 4; ++ni) {
      int col = bn * 128 + wn * 64 + ni * 16 + (lane & 15);
#pragma unroll
      for (int r = 0; r < 4; ++r)
        C[(long)(rbase + r) * N + col] = (OutT)acc[mi][ni][r];
    }
  }
}

// ---------------- dt: fp32 GEMV for the 32 dt columns + softplus ----------------
__global__ __launch_bounds__(256) void dt_kernel(
    const float* __restrict__ hs, const float* __restrict__ W1,
    const float* __restrict__ dt_bias, const float* __restrict__ A_log,
    float* __restrict__ dtb, float* __restrict__ adtb) {
  __shared__ float rowbuf[4][DMODEL];
  int r0 = blockIdx.x * 4;
  for (int e = threadIdx.x; e < 4 * DMODEL; e += 256)
    rowbuf[e >> 11][e & (DMODEL - 1)] = hs[(long)(r0 + (e >> 11)) * DMODEL + (e & (DMODEL - 1))];
  __syncthreads();
  int h = threadIdx.x >> 3, t = threadIdx.x & 7;
  const float* wr = W1 + (long)(CONVD + DMODEL + h) * DMODEL;
  float s[4] = {0.f, 0.f, 0.f, 0.f};
  for (int k = t * 4; k < DMODEL; k += 32) {
    float4 bv = *(const float4*)(wr + k);
#pragma unroll
    for (int r = 0; r < 4; ++r) {
      float4 av = *(const float4*)(&rowbuf[r][k]);
      s[r] += av.x * bv.x + av.y * bv.y + av.z * bv.z + av.w * bv.w;
    }
  }
#pragma unroll
  for (int r = 0; r < 4; ++r) {
    s[r] += __shfl_xor(s[r], 1, 64);
    s[r] += __shfl_xor(s[r], 2, 64);
    s[r] += __shfl_xor(s[r], 4, 64);
  }
  if (t == 0) {
    float na = -__expf(A_log[h]);
    float bias = dt_bias[h];
#pragma unroll
    for (int r = 0; r < 4; ++r) {
      float raw = s[r] + bias;
      float dtv = (raw > 20.0f) ? raw : log1pf(__expf(raw));
      dtb[(r0 + r) * NH + h] = dtv;
      adtb[(r0 + r) * NH + h] = na * dtv;
    }
  }
}

// ---------------- conv (k=2, causal) + SiLU (bf16 in/out) ----------------
__global__ __launch_bounds__(256) void conv_kernel(
    const bf16* __restrict__ proj, const float* __restrict__ conv_w,
    const float* __restrict__ conv_b, bf16* __restrict__ vkq) {
  int row = blockIdx.x;
  int l = row & (LSEQ - 1);
  const bf16* cur = proj + (long)row * NPADN;
  const bf16* prev = cur - NPADN;
  for (int c = threadIdx.x * 4; c < CONVD; c += 1024) {
    bf16x4 cu = *(const bf16x4*)(cur + c);
    bf16x4 pv = {};
    if (l > 0) pv = *(const bf16x4*)(prev + c);
    bf16x4 o;
#pragma unroll
    for (int u = 0; u < 4; ++u) {
      float x = (float)pv[u] * conv_w[(c + u) * 2 + 0] + (float)cu[u] * conv_w[(c + u) * 2 + 1] + conv_b[c + u];
      o[u] = (bf16)fsilu(x);
    }
    *(bf16x4*)(vkq + (long)row * CONVD + c) = o;
  }
}

// inclusive scan of 128 values in LDS (all 256 threads must call)
__device__ __forceinline__ void scan128(float* a, int tid) {
#pragma unroll
  for (int off = 1; off < CHUNK; off <<= 1) {
    float add = 0.f;
    if (tid >= off && tid < CHUNK) add = a[tid - off];
    __syncthreads();
    if (tid >= off && tid < CHUNK) a[tid] += add;
    __syncthreads();
  }
}

// ---------------- SSD phase A (MFMA): per-chunk states S[p][n] ----------------
__global__ __launch_bounds__(256) void ssd_states_kernel(
    const bf16* __restrict__ vkq, const float* __restrict__ dtb,
    const float* __restrict__ adtb, float* __restrict__ states, float* __restrict__ asum) {
  __shared__ __align__(16) bf16 Xt[64 * 136];
  __shared__ __align__(16) bf16 Kwt[64 * 136];
  __shared__ float acs[CHUNK];
  __shared__ float dts[CHUNK];
  int bid = blockIdx.x;                       // ((b*16 + c)*32 + h)
  int h = bid & 31, c = (bid >> 5) & 15, b = bid >> 9;
  int kvh = h >> 2;
  int tid = threadIdx.x;
  int lane = tid & 63, wave = tid >> 6;
  long rowbase = (long)b * LSEQ + c * CHUNK;
  if (tid < CHUNK) {
    acs[tid] = adtb[(rowbase + tid) * NH + h];
    dts[tid] = dtb[(rowbase + tid) * NH + h];
  }
  __syncthreads();
  scan128(acs, tid);
  float atot = acs[CHUNK - 1];
  for (int e = tid; e < CHUNK * HD; e += 256) {
    int j = e >> 6, p = e & 63;
    long roff = (rowbase + j) * (long)CONVD;
    float kv = (float)vkq[roff + 512 + kvh * HD + p] * __expf(atot - acs[j]);
    float xv = (float)vkq[roff + kvh * HD + p] * dts[j];
    Kwt[p * 136 + j] = (bf16)kv;
    Xt[p * 136 + j] = (bf16)xv;
  }
  __syncthreads();

  f32x4 sacc[4] = {};
#pragma unroll
  for (int ks = 0; ks < CHUNK; ks += 32) {
    bf16x8 af = *(const bf16x8*)(Xt + (wave * 16 + (lane & 15)) * 136 + ks + (lane >> 4) * 8);
    bf16x8 bf_[4];
#pragma unroll
    for (int ni = 0; ni < 4; ++ni)
      bf_[ni] = *(const bf16x8*)(Kwt + (ni * 16 + (lane & 15)) * 136 + ks + (lane >> 4) * 8);
#pragma unroll
    for (int ni = 0; ni < 4; ++ni)
      sacc[ni] = __builtin_amdgcn_mfma_f32_16x16x32_bf16(af, bf_[ni], sacc[ni], 0, 0, 0);
  }
  float* sout = states + (long)bid * (HD * HD);
#pragma unroll
  for (int ni = 0; ni < 4; ++ni) {
    int n = ni * 16 + (lane & 15);
#pragma unroll
    for (int r = 0; r < 4; ++r) {
      int p = wave * 16 + (lane >> 4) * 4 + r;
      sout[p * HD + n] = sacc[ni][r];
    }
  }
  if (tid == 0) asum[(b * NH + h) * NCHUNK + c] = atot;
}

// ---------------- SSD phase B: inter-chunk state scan ----------------
__global__ __launch_bounds__(256) void ssd_scan_kernel(
    const float* __restrict__ states, const float* __restrict__ asum,
    float* __restrict__ sprev) {
  int bid = blockIdx.x;                       // b*256 + h*8 + s
  int s = bid & 7, h = (bid >> 3) & 31, b = bid >> 8;
  int e0 = s * 512 + threadIdx.x;
  int e1 = e0 + 256;
  float S0 = 0.f, S1 = 0.f;
  const float* as = asum + (b * NH + h) * NCHUNK;
  for (int c = 0; c < NCHUNK; ++c) {
    long off = ((long)((b * NCHUNK + c) * NH + h)) * (HD * HD);
    float g = __expf(as[c]);
    sprev[off + e0] = S0;
    sprev[off + e1] = S1;
    S0 = S0 * g + states[off + e0];
    S1 = S1 * g + states[off + e1];
  }
}

// ---------------- SSD phase C (MFMA): Yd + Yo + RMSNorm + gate -> bf16 ----------------
__global__ __launch_bounds__(256) void ssd_out_kernel(
    const bf16* __restrict__ vkq, const bf16* __restrict__ proj,
    const float* __restrict__ dtb, const float* __restrict__ adtb,
    const float* __restrict__ sprev, const float* __restrict__ gnw,
    bf16* __restrict__ yg) {
  __shared__ __align__(16) bf16 Cq[128 * 72];
  __shared__ __align__(16) bf16 BmXt[128 * 72];  // Bm [j][n] s72; later Xt [p][j] s136
  __shared__ __align__(16) bf16 G[128 * 136];
  __shared__ __align__(16) bf16 Sp[64 * 72];
  __shared__ float acs[CHUNK];
  __shared__ float dts[CHUNK];
  __shared__ float part[CHUNK][2];
  __shared__ float rs_l[CHUNK];

  int bid = blockIdx.x;                       // ((b*16 + c)*32 + h)
  int h = bid & 31, c = (bid >> 5) & 15, b = bid >> 9;
  int kvh = h >> 2;
  int tid = threadIdx.x;
  int lane = tid & 63, wave = tid >> 6;
  int wm = wave >> 1, wn = wave & 1;
  long rowbase = (long)b * LSEQ + c * CHUNK;

  if (tid < CHUNK) {
    acs[tid] = adtb[(rowbase + tid) * NH + h];
    dts[tid] = dtb[(rowbase + tid) * NH + h];
  }
  for (int e = tid; e < CHUNK * HD; e += 256) {
    int j = e >> 6, p = e & 63;
    long roff = (rowbase + j) * (long)CONVD;
    Cq[j * 72 + p] = vkq[roff + 1024 + h * HD + p];
    BmXt[j * 72 + p] = vkq[roff + 512 + kvh * HD + p];
  }
  {
    long soff = ((long)((b * NCHUNK + c) * NH + h)) * (HD * HD);
    for (int e = tid; e < HD * HD; e += 256) Sp[(e >> 6) * 72 + (e & 63)] = (bf16)sprev[soff + e];
  }
  __syncthreads();
  scan128(acs, tid);

  // --- G = Cq . Bm^T  (128x128, K=64) ---
  {
    f32x4 gacc[4][4] = {};
#pragma unroll
    for (int ks = 0; ks < HD; ks += 32) {
      bf16x8 af[4], bf_[4];
#pragma unroll
      for (int mi = 0; mi < 4; ++mi)
        af[mi] = *(const bf16x8*)(Cq + (wm * 64 + mi * 16 + (lane & 15)) * 72 + ks + (lane >> 4) * 8);
#pragma unroll
      for (int ni = 0; ni < 4; ++ni)
        bf_[ni] = *(const bf16x8*)(BmXt + (wn * 64 + ni * 16 + (lane & 15)) * 72 + ks + (lane >> 4) * 8);
#pragma unroll
      for (int mi = 0; mi < 4; ++mi)
#pragma unroll
        for (int ni = 0; ni < 4; ++ni)
          gacc[mi][ni] = __builtin_amdgcn_mfma_f32_16x16x32_bf16(af[mi], bf_[ni], gacc[mi][ni], 0, 0, 0);
    }
#pragma unroll
    for (int mi = 0; mi < 4; ++mi) {
#pragma unroll
      for (int r = 0; r < 4; ++r) {
        int i = wm * 64 + mi * 16 + (lane >> 4) * 4 + r;
        float ai = acs[i];
#pragma unroll
        for (int ni = 0; ni < 4; ++ni) {
          int j = wn * 64 + ni * 16 + (lane & 15);
          float gv = (j <= i) ? gacc[mi][ni][r] * __expf(ai - acs[j]) : 0.f;
          G[i * 136 + j] = (bf16)gv;
        }
      }
    }
  }
  __syncthreads();

  // --- overwrite BmXt with Xt[p][j] = v[j][p] * dt[j], stride 136 ---
  for (int e = tid; e < CHUNK * HD; e += 256) {
    int j = e >> 6, p = e & 63;
    BmXt[p * 136 + j] = (bf16)((float)vkq[(rowbase + j) * (long)CONVD + kvh * HD + p] * dts[j]);
  }
  __syncthreads();

  // --- Yd = G . Xt^T (K=128); Yo = Cq . Sp^T (K=64) ---
  f32x4 yacc[4][2] = {};
  f32x4 oacc[4][2] = {};
#pragma unroll
  for (int ks = 0; ks < CHUNK; ks += 32) {
    bf16x8 af[4], bf_[2];
#pragma unroll
    for (int mi = 0; mi < 4; ++mi)
      af[mi] = *(const bf16x8*)(G + (wm * 64 + mi * 16 + (lane & 15)) * 136 + ks + (lane >> 4) * 8);
#pragma unroll
    for (int ni = 0; ni < 2; ++ni)
      bf_[ni] = *(const bf16x8*)(BmXt + (wn * 32 + ni * 16 + (lane & 15)) * 136 + ks + (lane >> 4) * 8);
#pragma unroll
    for (int mi = 0; mi < 4; ++mi)
#pragma unroll
      for (int ni = 0; ni < 2; ++ni)
        yacc[mi][ni] = __builtin_amdgcn_mfma_f32_16x16x32_bf16(af[mi], bf_[ni], yacc[mi][ni], 0, 0, 0);
  }
#pragma unroll
  for (int ks = 0; ks < HD; ks += 32) {
    bf16x8 af[4], bf_[2];
#pragma unroll
    for (int mi = 0; mi < 4; ++mi)
      af[mi] = *(const bf16x8*)(Cq + (wm * 64 + mi * 16 + (lane & 15)) * 72 + ks + (lane >> 4) * 8);
#pragma unroll
    for (int ni = 0; ni < 2; ++ni)
      bf_[ni] = *(const bf16x8*)(Sp + (wn * 32 + ni * 16 + (lane & 15)) * 72 + ks + (lane >> 4) * 8);
#pragma unroll
    for (int mi = 0; mi < 4; ++mi)
#pragma unroll
      for (int ni = 0; ni < 2; ++ni)
        oacc[mi][ni] = __builtin_amdgcn_mfma_f32_16x16x32_bf16(af[mi], bf_[ni], oacc[mi][ni], 0, 0, 0);
  }

  // --- combine, RMSNorm partials ---
  float yv[4][2][4];
#pragma unroll
  for (int mi = 0; mi < 4; ++mi) {
#pragma unroll
    for (int r = 0; r < 4; ++r) {
      int i = wm * 64 + mi * 16 + (lane >> 4) * 4 + r;
      float ei = __expf(acs[i]);
      float s = 0.f;
#pragma unroll
      for (int ni = 0; ni < 2; ++ni) {
        float v = yacc[mi][ni][r] + ei * oacc[mi][ni][r];
        yv[mi][ni][r] = v;
        s += v * v;
      }
      s += __shfl_xor(s, 1, 64);
      s += __shfl_xor(s, 2, 64);
      s += __shfl_xor(s, 4, 64);
      s += __shfl_xor(s, 8, 64);
      if ((lane & 15) == 0) part[i][wn] = s;
    }
  }
  __syncthreads();
  if (tid < CHUNK) rs_l[tid] = rsqrtf((part[tid][0] + part[tid][1]) * (1.0f / HD) + EPSF);
  __syncthreads();

#pragma unroll
  for (int mi = 0; mi < 4; ++mi) {
#pragma unroll
    for (int r = 0; r < 4; ++r) {
      int i = wm * 64 + mi * 16 + (lane >> 4) * 4 + r;
      long row = rowbase + i;
      float rs = rs_l[i];
#pragma unroll
      for (int ni = 0; ni < 2; ++ni) {
        int p = wn * 32 + ni * 16 + (lane & 15);
        float gval = (float)proj[row * (long)NPADN + CONVD + h * HD + p];
        float val = yv[mi][ni][r] * rs * gnw[p] * fsilu(gval);
        yg[row * (long)DMODEL + h * HD + p] = (bf16)val;
      }
    }
  }
}

// ---------------- launch ----------------
extern "C" void kernel_launch(void* const* d_in, const int* in_sizes, int n_in,
                              void* d_out, int out_size, void* d_ws, size_t ws_size,
                              hipStream_t stream) {
  const float* hs      = (const float*)d_in[0];
  const float* W1      = (const float*)d_in[1];
  const float* conv_w  = (const float*)d_in[2];
  const float* conv_b  = (const float*)d_in[3];
  const float* dt_bias = (const float*)d_in[4];
  const float* A_log   = (const float*)d_in[5];
  const float* gnw     = (const float*)d_in[6];
  const float* Wo      = (const float*)d_in[7];

  char* p = (char*)d_ws;
  bf16* hs_b   = (bf16*)p;  p += (long)ROWS * DMODEL * 2;
  bf16* w1_b   = (bf16*)p;  p += (long)NPADN * DMODEL * 2;
  bf16* wo_b   = (bf16*)p;  p += (long)DMODEL * DMODEL * 2;
  bf16* proj   = (bf16*)p;  p += (long)ROWS * NPADN * 2;
  bf16* vkq    = (bf16*)p;  p += (long)ROWS * CONVD * 2;
  float* dtb   = (float*)p; p += (long)ROWS * NH * 4;
  float* adtb  = (float*)p; p += (long)ROWS * NH * 4;
  float* st    = (float*)p; p += (long)NB * NCHUNK * NH * HD * HD * 4;
  float* sprev = (float*)p; p += (long)NB * NCHUNK * NH * HD * HD * 4;
  float* asum  = (float*)p; p += (long)NB * NH * NCHUNK * 4;
  bf16* yg     = (bf16*)p;  p += (long)ROWS * DMODEL * 2;

  cast_bf16_kernel<<<2048, 256, 0, stream>>>(hs, hs_b, ROWS * DMODEL);
  cast_w1_kernel<<<2048, 256, 0, stream>>>(W1, w1_b);
  cast_bf16_kernel<<<1024, 256, 0, stream>>>(Wo, wo_b, DMODEL * DMODEL);

  gemm_bt_kernel<bf16><<<(ROWS / 128) * (NPADN / 128), 256, 0, stream>>>(
      hs_b, w1_b, proj, ROWS, NPADN, DMODEL, NPADN / 128);

  dt_kernel<<<ROWS / 4, 256, 0, stream>>>(hs, W1, dt_bias, A_log, dtb, adtb);

  conv_kernel<<<ROWS, 256, 0, stream>>>(proj, conv_w, conv_b, vkq);

  ssd_states_kernel<<<NB * NCHUNK * NH, 256, 0, stream>>>(vkq, dtb, adtb, st, asum);
  ssd_scan_kernel<<<NB * NH * 8, 256, 0, stream>>>(st, asum, sprev);
  ssd_out_kernel<<<NB * NCHUNK * NH, 256, 0, stream>>>(vkq, proj, dtb, adtb, sprev, gnw, yg);

  gemm_bt_kernel<float><<<(ROWS / 128) * (DMODEL / 128), 256, 0, stream>>>(
      yg, wo_b, (float*)d_out, ROWS, DMODEL, DMODEL, DMODEL / 128);
}